// Round 5
// baseline (26.127 us; speedup 1.0000x reference)
//
#include <hip/hip_runtime.h>
#include <math.h>

// PositionalEncoding: out = x * sqrt(512) + pe, pe interleaved sin/cos of
// positions[b,s] * div_term[i], div_term[i] = 10000^(-i/256), d_model = 512.
//
// Memory-bound elementwise op (~134 MB traffic, floor ~21.4 us @ 6.29 TB/s
// copy ceiling). Max-MLP structure: each wave covers 2 full rows (256
// consecutive f4); each thread issues 4 independent 16B NT loads up front
// (64 B/lane in flight), computes all trig, then 4 NT stores.
//   - only ONE v_exp per thread: dt set shared by both rows; cols j+64 use
//     dt*0.01 exactly (10000^(-128/256) = 1/100).
//   - positions via 2 scalar loads (wave-uniform rows).

#define D_MODEL 512

typedef float f32x4 __attribute__((ext_vector_type(4)));

__global__ __launch_bounds__(256) void pe_kernel(
    const f32x4* __restrict__ x,
    const int*   __restrict__ positions,
    f32x4*       __restrict__ out)
{
    const float SQRT_D   = 22.627416997969522f;       // sqrt(512)
    const float C2       = -0.05190512364928082f;     // -log2(10000)/256
    const float INV2PI   = 0.15915494309189535f;      // 1/(2*pi)
    const float DT_RATIO = 0.9646616199111993f;       // 10000^(-1/256)

    int t    = blockIdx.x * blockDim.x + threadIdx.x;
    int wid  = __builtin_amdgcn_readfirstlane(t >> 6); // wave id -> SGPR
    int lane = t & 63;
    int r0i  = wid * 2;                                // first row of the pair
    long base = (long)r0i * 128 + lane;                // f4 index

    // 4 independent loads, issued back-to-back (64 B/lane in flight)
    f32x4 v0 = __builtin_nontemporal_load(&x[base]);        // row0, col lane
    f32x4 v1 = __builtin_nontemporal_load(&x[base + 64]);   // row0, col lane+64
    f32x4 v2 = __builtin_nontemporal_load(&x[base + 128]);  // row1, col lane
    f32x4 v3 = __builtin_nontemporal_load(&x[base + 192]);  // row1, col lane+64

    float prA = (float)positions[r0i]     * INV2PI;    // scalar, broadcast
    float prB = (float)positions[r0i + 1] * INV2PI;

    // div_terms for f4-col lane: pairs (2*lane, 2*lane+1); col lane+64 -> *0.01
    float dt0 = __builtin_amdgcn_exp2f((float)(2 * lane) * C2);
    float dt1 = dt0 * DT_RATIO;
    float dt2 = dt0 * 0.01f;
    float dt3 = dt1 * 0.01f;

#define RED(p, d) ({ float _r = (p) * (d); _r - floorf(_r); })
    float a0 = RED(prA, dt0), a1 = RED(prA, dt1), a2 = RED(prA, dt2), a3 = RED(prA, dt3);
    float b0 = RED(prB, dt0), b1 = RED(prB, dt1), b2 = RED(prB, dt2), b3 = RED(prB, dt3);
#undef RED

    f32x4 o0, o1, o2, o3;
    o0.x = v0.x * SQRT_D + __builtin_amdgcn_sinf(a0);
    o0.y = v0.y * SQRT_D + __builtin_amdgcn_cosf(a0);
    o0.z = v0.z * SQRT_D + __builtin_amdgcn_sinf(a1);
    o0.w = v0.w * SQRT_D + __builtin_amdgcn_cosf(a1);
    o1.x = v1.x * SQRT_D + __builtin_amdgcn_sinf(a2);
    o1.y = v1.y * SQRT_D + __builtin_amdgcn_cosf(a2);
    o1.z = v1.z * SQRT_D + __builtin_amdgcn_sinf(a3);
    o1.w = v1.w * SQRT_D + __builtin_amdgcn_cosf(a3);
    o2.x = v2.x * SQRT_D + __builtin_amdgcn_sinf(b0);
    o2.y = v2.y * SQRT_D + __builtin_amdgcn_cosf(b0);
    o2.z = v2.z * SQRT_D + __builtin_amdgcn_sinf(b1);
    o2.w = v2.w * SQRT_D + __builtin_amdgcn_cosf(b1);
    o3.x = v3.x * SQRT_D + __builtin_amdgcn_sinf(b2);
    o3.y = v3.y * SQRT_D + __builtin_amdgcn_cosf(b2);
    o3.z = v3.z * SQRT_D + __builtin_amdgcn_sinf(b3);
    o3.w = v3.w * SQRT_D + __builtin_amdgcn_cosf(b3);

    __builtin_nontemporal_store(o0, &out[base]);
    __builtin_nontemporal_store(o1, &out[base + 64]);
    __builtin_nontemporal_store(o2, &out[base + 128]);
    __builtin_nontemporal_store(o3, &out[base + 192]);
}

extern "C" void kernel_launch(void* const* d_in, const int* in_sizes, int n_in,
                              void* d_out, int out_size, void* d_ws, size_t ws_size,
                              hipStream_t stream) {
    const float* x   = (const float*)d_in[0];
    const int*   pos = (const int*)d_in[1];
    float*       out = (float*)d_out;

    int nrows = out_size / D_MODEL;        // 32768 rows
    int block = 256;
    int grid  = nrows / 8;                 // 2 rows/wave, 4 waves/block -> 4096
    pe_kernel<<<grid, block, 0, stream>>>(
        (const f32x4*)x, pos, (f32x4*)out);
}